// Round 1
// baseline (442.561 us; speedup 1.0000x reference)
//
#include <hip/hip_runtime.h>

// GraphEmbeddings interaction network, fp32.
// B=64 batches, P=128 nodes, F=16 features. E = P*(P-1) = 16256 edges/batch.
// fr: 32 -> 96 -> 64 -> 32 (Dense+BN+ReLU), scatter-add to receiver.
// fo: 48 -> 64 -> 32 (Dense+BN+ReLU), sum over nodes -> (B, 32).
//
// Restructuring:
//  - fr0 factors through nodes: concat(x_recv, x_send)@W0 = R[recv] + S[send].
//  - BN folded: relu(h*s + c), s = g*rsqrt(var+eps), c = (bias-mu)*s + beta.
//  - One block per (batch, receiver): sums 127 senders in registers, no atomics,
//    deterministic order.

#define NB 64
#define NF 16
#define NP 128

// ---------------- fold BN constants ----------------
__global__ void fold_bn(const float* __restrict__ b, const float* __restrict__ g,
                        const float* __restrict__ beta, const float* __restrict__ mu,
                        const float* __restrict__ var, float* __restrict__ s_out,
                        float* __restrict__ c_out, int n) {
    int t = threadIdx.x;
    if (t < n) {
        float s = g[t] * rsqrtf(var[t] + 1e-3f);
        s_out[t] = s;
        c_out[t] = (b[t] - mu[t]) * s + beta[t];
    }
}

// ---------------- per-node first-layer partials ----------------
// R[node][ch] = x_node @ W0[0:16, ch] ; S[node][ch] = x_node @ W0[16:32, ch]
__global__ void rs_kernel(const float* __restrict__ x, const float* __restrict__ w0,
                          float* __restrict__ R, float* __restrict__ S) {
    int idx = blockIdx.x * blockDim.x + threadIdx.x; // B*P*96
    if (idx >= NB * NP * 96) return;
    int ch = idx % 96;
    int node = idx / 96;
    int p = node & (NP - 1);
    int b = node >> 7;
    const float* xb = x + (b * NF) * NP + p;
    float r = 0.f, s = 0.f;
#pragma unroll
    for (int f = 0; f < NF; ++f) {
        float xv = xb[f * NP];          // broadcast within wave
        r += xv * w0[f * 96 + ch];      // coalesced
        s += xv * w0[(NF + f) * 96 + ch];
    }
    R[idx] = r;
    S[idx] = s;
}

// ---------------- edge MLP + scatter-add (the hot kernel) ----------------
// Block = (batch b, receiver p). 256 threads = 4 waves.
// lane (0..63) = edge-in-chunk, wave w owns output channels [w*16,w*16+16) of fr1
// and [w*8,w*8+8) of fr2. W1/W2/BN-consts indexed wave-uniformly -> scalar loads.
__global__ __launch_bounds__(256) void edge_mlp(
    const float* __restrict__ Rg, const float* __restrict__ Sg,
    const float* __restrict__ w1,  // fr1_w (96 x 64)
    const float* __restrict__ w2,  // fr2_w (64 x 32)
    const float* __restrict__ cs,  // folded consts
    float* __restrict__ agg)       // [B*P][32]
{
    __shared__ float E1[64 * 97];   // padded stride 97 -> conflict-free lane reads
    __shared__ float E2[64 * 65];
    __shared__ float Rl[96], s0l[96], c0l[96];

    const int tid = threadIdx.x;
    const int blk = blockIdx.x;          // b*128 + p
    const int b = blk >> 7;
    const int p = blk & (NP - 1);

    if (tid < 96) {
        Rl[tid]  = Rg[(size_t)blk * 96 + tid];
        s0l[tid] = cs[tid];
        c0l[tid] = cs[96 + tid];
    }
    __syncthreads();

    const int lane = tid & 63;
    const int w = __builtin_amdgcn_readfirstlane(tid >> 6);

    float racc[8];
#pragma unroll
    for (int j = 0; j < 8; ++j) racc[j] = 0.f;

    const float* Sb = Sg + (size_t)b * NP * 96;

    for (int chunk = 0; chunk < 2; ++chunk) {
        // ---- Phase A: E1 = relu((R[recv] + S[send]) * s0 + c0) ----
        for (int i = tid; i < 64 * 96; i += 256) {
            int e = i / 96;
            int ch = i - e * 96;
            int ge = chunk * 64 + e;          // global edge 0..127
            if (ge < 127) {
                int a = ge + (ge >= p ? 1 : 0);  // sender node
                float v = (Rl[ch] + Sb[a * 96 + ch]) * s0l[ch] + c0l[ch];
                E1[e * 97 + ch] = fmaxf(v, 0.f);
            }
        }
        __syncthreads();

        // ---- Phase B: E2 = relu((E1 @ W1) * s1 + c1), wave w -> o in [16w,16w+16) ----
        float acc[16];
#pragma unroll
        for (int j = 0; j < 16; ++j) acc[j] = 0.f;
        const float* w1p = w1 + w * 16;
#pragma unroll 2
        for (int k = 0; k < 96; ++k) {
            float ev = E1[lane * 97 + k];          // conflict-free LDS
            const float* wr = w1p + k * 64;        // wave-uniform -> s_load
#pragma unroll
            for (int j = 0; j < 16; ++j) acc[j] += ev * wr[j];
        }
#pragma unroll
        for (int j = 0; j < 16; ++j) {
            int o = w * 16 + j;
            float v = fmaxf(acc[j] * cs[192 + o] + cs[256 + o], 0.f);
            E2[lane * 65 + o] = v;
        }
        __syncthreads();

        // ---- Phase C: E3 = relu((E2 @ W2) * s2 + c2); accumulate over edges ----
        float acc3[8];
#pragma unroll
        for (int j = 0; j < 8; ++j) acc3[j] = 0.f;
        const float* w2p = w2 + w * 8;
#pragma unroll 2
        for (int k = 0; k < 64; ++k) {
            float ev = E2[lane * 65 + k];
            const float* wr = w2p + k * 32;
#pragma unroll
            for (int j = 0; j < 8; ++j) acc3[j] += ev * wr[j];
        }
        int ge = chunk * 64 + lane;
        if (ge < 127) {
#pragma unroll
            for (int j = 0; j < 8; ++j) {
                int m = w * 8 + j;
                racc[j] += fmaxf(acc3[j] * cs[320 + m] + cs[352 + m], 0.f);
            }
        }
        // next chunk's Phase A may overwrite E1: safe, all waves passed the
        // A->B barrier of this chunk (B done) and C only touches E2.
    }

    // deterministic wave reduction over 64 lanes; wave w writes its 8 channels
#pragma unroll
    for (int j = 0; j < 8; ++j) {
        float v = racc[j];
#pragma unroll
        for (int d = 32; d >= 1; d >>= 1) v += __shfl_xor(v, d, 64);
        if (lane == 0) agg[(size_t)blk * 32 + w * 8 + j] = v;
    }
}

// ---------------- per-node fo MLP ----------------
__global__ void fo_kernel(const float* __restrict__ x, const float* __restrict__ agg,
                          const float* __restrict__ fo0w, const float* __restrict__ fo1w,
                          const float* __restrict__ cs, float* __restrict__ fo_out) {
    int blk = blockIdx.x;            // b*128 + p
    int b = blk >> 7;
    int p = blk & (NP - 1);
    __shared__ float h[48];
    __shared__ float h2[64];
    int t = threadIdx.x;             // 64 threads
    if (t < NF) h[t] = x[(b * NF + t) * NP + p];
    else if (t < 48) h[t] = agg[blk * 32 + (t - NF)];
    __syncthreads();
    float a = 0.f;
#pragma unroll 4
    for (int k = 0; k < 48; ++k) a += h[k] * fo0w[k * 64 + t];
    h2[t] = fmaxf(a * cs[384 + t] + cs[448 + t], 0.f);
    __syncthreads();
    if (t < 32) {
        float a2 = 0.f;
#pragma unroll 4
        for (int k = 0; k < 64; ++k) a2 += h2[k] * fo1w[k * 32 + t];
        fo_out[blk * 32 + t] = fmaxf(a2 * cs[512 + t] + cs[544 + t], 0.f);
    }
}

// ---------------- deterministic sum over nodes ----------------
__global__ void reduce_kernel(const float* __restrict__ fo_out, float* __restrict__ out) {
    int b = blockIdx.x;              // 64 blocks
    int t = threadIdx.x;             // 256
    int m = t & 31;
    int g = t >> 5;                  // 8 groups
    float v = 0.f;
    for (int p = g; p < NP; p += 8) v += fo_out[(b * NP + p) * 32 + m];
    __shared__ float red[256];
    red[t] = v;
    __syncthreads();
    for (int s = 4; s >= 1; s >>= 1) {
        if (g < s) red[t] += red[t + s * 32];
        __syncthreads();
    }
    if (g == 0) out[b * 32 + m] = red[t];
}

extern "C" void kernel_launch(void* const* d_in, const int* in_sizes, int n_in,
                              void* d_out, int out_size, void* d_ws, size_t ws_size,
                              hipStream_t stream) {
    (void)in_sizes; (void)n_in; (void)out_size; (void)ws_size;
    const float* x    = (const float*)d_in[0];
    const float* fr0w = (const float*)d_in[1];
    const float* fr1w = (const float*)d_in[7];
    const float* fr2w = (const float*)d_in[13];
    const float* fo0w = (const float*)d_in[19];
    const float* fo1w = (const float*)d_in[25];

    float* ws     = (float*)d_ws;
    float* cs     = ws;                        // 576 floats (pad to 1024)
    float* R      = ws + 1024;                 // B*P*96
    float* S      = R + NB * NP * 96;          // B*P*96
    float* agg    = S + NB * NP * 96;          // B*P*32
    float* fo_out = agg + NB * NP * 32;        // B*P*32
    float* out    = (float*)d_out;

    // fold BN for the 5 layers: (b,g,beta,mu,var) at in-index base+1..base+5
    fold_bn<<<1, 96, 0, stream>>>((const float*)d_in[2],  (const float*)d_in[3],
                                  (const float*)d_in[4],  (const float*)d_in[5],
                                  (const float*)d_in[6],  cs + 0,   cs + 96, 96);
    fold_bn<<<1, 64, 0, stream>>>((const float*)d_in[8],  (const float*)d_in[9],
                                  (const float*)d_in[10], (const float*)d_in[11],
                                  (const float*)d_in[12], cs + 192, cs + 256, 64);
    fold_bn<<<1, 32, 0, stream>>>((const float*)d_in[14], (const float*)d_in[15],
                                  (const float*)d_in[16], (const float*)d_in[17],
                                  (const float*)d_in[18], cs + 320, cs + 352, 32);
    fold_bn<<<1, 64, 0, stream>>>((const float*)d_in[20], (const float*)d_in[21],
                                  (const float*)d_in[22], (const float*)d_in[23],
                                  (const float*)d_in[24], cs + 384, cs + 448, 64);
    fold_bn<<<1, 32, 0, stream>>>((const float*)d_in[26], (const float*)d_in[27],
                                  (const float*)d_in[28], (const float*)d_in[29],
                                  (const float*)d_in[30], cs + 512, cs + 544, 32);

    rs_kernel<<<(NB * NP * 96 + 255) / 256, 256, 0, stream>>>(x, fr0w, R, S);

    edge_mlp<<<NB * NP, 256, 0, stream>>>(R, S, fr1w, fr2w, cs, agg);

    fo_kernel<<<NB * NP, 64, 0, stream>>>(x, agg, fo0w, fo1w, cs, fo_out);

    reduce_kernel<<<NB, 256, 0, stream>>>(fo_out, out);
}

// Round 2
// 91.976 us; speedup vs baseline: 4.8117x; 4.8117x over previous
//
#include <hip/hip_runtime.h>

// GraphEmbeddings interaction network — MFMA bf16 version.
// B=64, P=128, F=16. Per (b, receiver p) block: M=128 senders (self-edge
// included in the GEMMs, excluded from the final sum), fr1 (96->64) and
// fr2 (64->32) as mfma_f32_16x16x32_bf16 GEMMs, fp32 accumulation.
// fr0 factors through nodes: Rc = (x@W0r)*s0+c0, Sc = (x@W0s)*s0 precomputed.

#define NB 64
#define NF 16
#define NP 128

typedef __bf16 bf16x8 __attribute__((ext_vector_type(8)));
typedef __bf16 bf16x4 __attribute__((ext_vector_type(4)));
typedef float  f32x4  __attribute__((ext_vector_type(4)));

// ---------------- fold BN constants ----------------
__global__ void fold_bn(const float* __restrict__ b, const float* __restrict__ g,
                        const float* __restrict__ beta, const float* __restrict__ mu,
                        const float* __restrict__ var, float* __restrict__ s_out,
                        float* __restrict__ c_out, int n) {
    int t = threadIdx.x;
    if (t < n) {
        float s = g[t] * rsqrtf(var[t] + 1e-3f);
        s_out[t] = s;
        c_out[t] = (b[t] - mu[t]) * s + beta[t];
    }
}

// ---------------- pack W1/W2 into MFMA B-fragment layout, bf16 ----------------
// w1f[kb][n][j] = bf16(W1[kb*8+j][n])  kb<12, n<64, j<8
// w2f[kb][n][j] = bf16(W2[kb*8+j][n])  kb<8,  n<32, j<8
__global__ void prep_w(const float* __restrict__ w1, const float* __restrict__ w2,
                       __bf16* __restrict__ w1f, __bf16* __restrict__ w2f) {
    int i = blockIdx.x * 256 + threadIdx.x;
    if (i < 12 * 64 * 8) {
        int j = i & 7, n = (i >> 3) & 63, kb = i >> 9;
        w1f[i] = (__bf16)w1[(kb * 8 + j) * 64 + n];
    }
    if (i < 8 * 32 * 8) {
        int j = i & 7, n = (i >> 3) & 31, kb = i >> 8;
        w2f[i] = (__bf16)w2[(kb * 8 + j) * 32 + n];
    }
}

// ---------------- per-node first-layer partials (BN0 folded in) ----------------
// Rc[node][ch] = (x_node @ W0[0:16,ch])*s0+c0 ; Sc[node][ch] = (x_node @ W0[16:32,ch])*s0
__global__ void rs_kernel(const float* __restrict__ x, const float* __restrict__ w0,
                          const float* __restrict__ cs,
                          float* __restrict__ Rc, float* __restrict__ Sc) {
    int idx = blockIdx.x * blockDim.x + threadIdx.x; // B*P*96
    if (idx >= NB * NP * 96) return;
    int ch = idx % 96;
    int node = idx / 96;
    int p = node & (NP - 1);
    int b = node >> 7;
    const float* xb = x + (b * NF) * NP + p;
    float r = 0.f, s = 0.f;
#pragma unroll
    for (int f = 0; f < NF; ++f) {
        float xv = xb[f * NP];
        r += xv * w0[f * 96 + ch];
        s += xv * w0[(NF + f) * 96 + ch];
    }
    float s0 = cs[ch], c0 = cs[96 + ch];
    Rc[idx] = r * s0 + c0;
    Sc[idx] = s * s0;
}

// ---------------- edge MLP via MFMA (the hot kernel) ----------------
// Block = (b, p). 256 threads = 4 waves. Wave w owns rows 32w..32w+31.
// E1 LDS stride 104 bf16 (208B, 16B-aligned rows, 2 lanes/bank on b128 reads).
// E2 LDS stride 72 bf16 (144B rows).
__global__ __launch_bounds__(256) void edge_mlp_mfma(
    const float* __restrict__ Rc, const float* __restrict__ Sc,
    const __bf16* __restrict__ w1f, const __bf16* __restrict__ w2f,
    const float* __restrict__ cs, float* __restrict__ agg)
{
    __shared__ __bf16 E1[128 * 104];
    __shared__ __bf16 E2[128 * 72];
    __shared__ float  Rcl[96];
    __shared__ float  red[128];

    const int tid = threadIdx.x;
    const int blk = blockIdx.x;        // b*128 + p
    const int b   = blk >> 7;
    const int p   = blk & 127;
    const int lane = tid & 63;
    const int w    = tid >> 6;
    const int g    = lane >> 4;
    const int l15  = lane & 15;

    // ---- preload W fragments into registers (latency hidden under phase A) ----
    const bf16x8* W1v = (const bf16x8*)w1f;  // [12*64] fragments of 8
    const bf16x8* W2v = (const bf16x8*)w2f;  // [8*32]
    bf16x8 bw1[3][4];
#pragma unroll
    for (int ks = 0; ks < 3; ++ks)
#pragma unroll
        for (int nt = 0; nt < 4; ++nt)
            bw1[ks][nt] = W1v[(ks * 4 + g) * 64 + nt * 16 + l15];
    bf16x8 bw2[2][2];
#pragma unroll
    for (int ks = 0; ks < 2; ++ks)
#pragma unroll
        for (int nt = 0; nt < 2; ++nt)
            bw2[ks][nt] = W2v[(ks * 4 + g) * 32 + nt * 16 + l15];

    if (tid < 96) Rcl[tid] = Rc[(size_t)blk * 96 + tid];
    __syncthreads();

    // ---- Phase A: E1[a][ch] = relu(Rc[ch] + Sc[a][ch]) -> bf16 ----
    const float4* Sb = (const float4*)(Sc + (size_t)b * NP * 96);
#pragma unroll
    for (int it = 0; it < 12; ++it) {
        int idx = tid + it * 256;          // 0..3071 float4s
        int row = idx / 24;
        int c4  = idx - row * 24;
        float4 sv = Sb[idx];
        float4 rv = *(const float4*)&Rcl[c4 * 4];
        bf16x4 o;
        o[0] = (__bf16)fmaxf(rv.x + sv.x, 0.f);
        o[1] = (__bf16)fmaxf(rv.y + sv.y, 0.f);
        o[2] = (__bf16)fmaxf(rv.z + sv.z, 0.f);
        o[3] = (__bf16)fmaxf(rv.w + sv.w, 0.f);
        *(bf16x4*)&E1[row * 104 + c4 * 4] = o;
    }
    __syncthreads();

    // ---- fr1: C1[128x64] = E1[128x96] @ W1[96x64] ----
    f32x4 acc[2][4];
#pragma unroll
    for (int mt = 0; mt < 2; ++mt)
#pragma unroll
        for (int nt = 0; nt < 4; ++nt)
            acc[mt][nt] = (f32x4){0.f, 0.f, 0.f, 0.f};
#pragma unroll
    for (int ks = 0; ks < 3; ++ks) {
#pragma unroll
        for (int mt = 0; mt < 2; ++mt) {
            bf16x8 af = *(const bf16x8*)&E1[(32 * w + 16 * mt + l15) * 104 + ks * 32 + g * 8];
#pragma unroll
            for (int nt = 0; nt < 4; ++nt)
                acc[mt][nt] = __builtin_amdgcn_mfma_f32_16x16x32_bf16(af, bw1[ks][nt], acc[mt][nt], 0, 0, 0);
        }
    }

    // ---- epilogue 1: E2 = relu(C1*s1+c1) -> bf16 LDS (wave-private rows) ----
    float s1v[4], c1v[4];
#pragma unroll
    for (int nt = 0; nt < 4; ++nt) {
        s1v[nt] = cs[192 + nt * 16 + l15];
        c1v[nt] = cs[256 + nt * 16 + l15];
    }
#pragma unroll
    for (int mt = 0; mt < 2; ++mt)
#pragma unroll
        for (int nt = 0; nt < 4; ++nt)
#pragma unroll
            for (int r = 0; r < 4; ++r) {
                int row = 32 * w + 16 * mt + 4 * g + r;
                E2[row * 72 + nt * 16 + l15] =
                    (__bf16)fmaxf(acc[mt][nt][r] * s1v[nt] + c1v[nt], 0.f);
            }
    __syncthreads();

    // ---- fr2: C2[128x32] = E2[128x64] @ W2[64x32] ----
    f32x4 acc2[2][2];
#pragma unroll
    for (int mt = 0; mt < 2; ++mt)
#pragma unroll
        for (int nt = 0; nt < 2; ++nt)
            acc2[mt][nt] = (f32x4){0.f, 0.f, 0.f, 0.f};
#pragma unroll
    for (int ks = 0; ks < 2; ++ks) {
#pragma unroll
        for (int mt = 0; mt < 2; ++mt) {
            bf16x8 af = *(const bf16x8*)&E2[(32 * w + 16 * mt + l15) * 72 + ks * 32 + g * 8];
#pragma unroll
            for (int nt = 0; nt < 2; ++nt)
                acc2[mt][nt] = __builtin_amdgcn_mfma_f32_16x16x32_bf16(af, bw2[ks][nt], acc2[mt][nt], 0, 0, 0);
        }
    }

    // ---- epilogue 2: E3 = relu(C2*s2+c2); sum over rows != p ----
    float s2v[2], c2v[2];
#pragma unroll
    for (int nt = 0; nt < 2; ++nt) {
        s2v[nt] = cs[320 + nt * 16 + l15];
        c2v[nt] = cs[352 + nt * 16 + l15];
    }
    float sum0 = 0.f, sum1 = 0.f;
#pragma unroll
    for (int mt = 0; mt < 2; ++mt)
#pragma unroll
        for (int r = 0; r < 4; ++r) {
            int row = 32 * w + 16 * mt + 4 * g + r;
            float v0 = fmaxf(acc2[mt][0][r] * s2v[0] + c2v[0], 0.f);
            float v1 = fmaxf(acc2[mt][1][r] * s2v[1] + c2v[1], 0.f);
            if (row != p) { sum0 += v0; sum1 += v1; }
        }
    sum0 += __shfl_xor(sum0, 16, 64);
    sum0 += __shfl_xor(sum0, 32, 64);
    sum1 += __shfl_xor(sum1, 16, 64);
    sum1 += __shfl_xor(sum1, 32, 64);
    if (lane < 16) {
        red[w * 32 + l15]      = sum0;
        red[w * 32 + 16 + l15] = sum1;
    }
    __syncthreads();
    if (tid < 32)
        agg[(size_t)blk * 32 + tid] = red[tid] + red[32 + tid] + red[64 + tid] + red[96 + tid];
}

// ---------------- per-node fo MLP ----------------
__global__ void fo_kernel(const float* __restrict__ x, const float* __restrict__ agg,
                          const float* __restrict__ fo0w, const float* __restrict__ fo1w,
                          const float* __restrict__ cs, float* __restrict__ fo_out) {
    int blk = blockIdx.x;            // b*128 + p
    int b = blk >> 7;
    int p = blk & (NP - 1);
    __shared__ float h[48];
    __shared__ float h2[64];
    int t = threadIdx.x;             // 64 threads
    if (t < NF) h[t] = x[(b * NF + t) * NP + p];
    else if (t < 48) h[t] = agg[blk * 32 + (t - NF)];
    __syncthreads();
    float a = 0.f;
#pragma unroll 4
    for (int k = 0; k < 48; ++k) a += h[k] * fo0w[k * 64 + t];
    h2[t] = fmaxf(a * cs[384 + t] + cs[448 + t], 0.f);
    __syncthreads();
    if (t < 32) {
        float a2 = 0.f;
#pragma unroll 4
        for (int k = 0; k < 64; ++k) a2 += h2[k] * fo1w[k * 32 + t];
        fo_out[blk * 32 + t] = fmaxf(a2 * cs[512 + t] + cs[544 + t], 0.f);
    }
}

// ---------------- deterministic sum over nodes ----------------
__global__ void reduce_kernel(const float* __restrict__ fo_out, float* __restrict__ out) {
    int b = blockIdx.x;              // 64 blocks
    int t = threadIdx.x;             // 256
    int m = t & 31;
    int g = t >> 5;                  // 8 groups
    float v = 0.f;
    for (int p = g; p < NP; p += 8) v += fo_out[(b * NP + p) * 32 + m];
    __shared__ float red[256];
    red[t] = v;
    __syncthreads();
    for (int s = 4; s >= 1; s >>= 1) {
        if (g < s) red[t] += red[t + s * 32];
        __syncthreads();
    }
    if (g == 0) out[b * 32 + m] = red[t];
}

extern "C" void kernel_launch(void* const* d_in, const int* in_sizes, int n_in,
                              void* d_out, int out_size, void* d_ws, size_t ws_size,
                              hipStream_t stream) {
    (void)in_sizes; (void)n_in; (void)out_size; (void)ws_size;
    const float* x    = (const float*)d_in[0];
    const float* fr0w = (const float*)d_in[1];
    const float* fr1w = (const float*)d_in[7];
    const float* fr2w = (const float*)d_in[13];
    const float* fo0w = (const float*)d_in[19];
    const float* fo1w = (const float*)d_in[25];

    float* ws     = (float*)d_ws;
    float* cs     = ws;                        // 1024 floats
    float* Rc     = ws + 1024;                 // B*P*96
    float* Sc     = Rc + NB * NP * 96;         // B*P*96
    __bf16* w1f   = (__bf16*)(Sc + NB * NP * 96);   // 6144 bf16 = 3072 floats
    __bf16* w2f   = (__bf16*)(Sc + NB * NP * 96 + 3072); // 2048 bf16 = 1024 floats
    float* agg    = Sc + NB * NP * 96 + 4096;  // B*P*32
    float* fo_out = agg + NB * NP * 32;        // B*P*32
    float* out    = (float*)d_out;

    fold_bn<<<1, 96, 0, stream>>>((const float*)d_in[2],  (const float*)d_in[3],
                                  (const float*)d_in[4],  (const float*)d_in[5],
                                  (const float*)d_in[6],  cs + 0,   cs + 96, 96);
    fold_bn<<<1, 64, 0, stream>>>((const float*)d_in[8],  (const float*)d_in[9],
                                  (const float*)d_in[10], (const float*)d_in[11],
                                  (const float*)d_in[12], cs + 192, cs + 256, 64);
    fold_bn<<<1, 32, 0, stream>>>((const float*)d_in[14], (const float*)d_in[15],
                                  (const float*)d_in[16], (const float*)d_in[17],
                                  (const float*)d_in[18], cs + 320, cs + 352, 32);
    fold_bn<<<1, 64, 0, stream>>>((const float*)d_in[20], (const float*)d_in[21],
                                  (const float*)d_in[22], (const float*)d_in[23],
                                  (const float*)d_in[24], cs + 384, cs + 448, 64);
    fold_bn<<<1, 32, 0, stream>>>((const float*)d_in[26], (const float*)d_in[27],
                                  (const float*)d_in[28], (const float*)d_in[29],
                                  (const float*)d_in[30], cs + 512, cs + 544, 32);

    prep_w<<<24, 256, 0, stream>>>(fr1w, fr2w, w1f, w2f);

    rs_kernel<<<(NB * NP * 96 + 255) / 256, 256, 0, stream>>>(x, fr0w, cs, Rc, Sc);

    edge_mlp_mfma<<<NB * NP, 256, 0, stream>>>(Rc, Sc, w1f, w2f, cs, agg);

    fo_kernel<<<NB * NP, 64, 0, stream>>>(x, agg, fo0w, fo1w, cs, fo_out);

    reduce_kernel<<<NB, 256, 0, stream>>>(fo_out, out);
}